// Round 6
// baseline (296.481 us; speedup 1.0000x reference)
//
#include <hip/hip_runtime.h>

#define NH    16
#define HD    64
#define SQ    2048
#define SKV   2048
#define DM    1024

typedef __attribute__((ext_vector_type(8))) __bf16 bf16x8;
typedef __attribute__((ext_vector_type(4))) __bf16 bf16x4;
typedef __attribute__((ext_vector_type(2))) __bf16 bf16x2;
typedef __attribute__((ext_vector_type(4))) float  f32x4;

// async global->LDS, 16B per lane; LDS dest = wave-uniform base + lane*16
#define ASYNC16(gp, lp)                                                        \
    __builtin_amdgcn_global_load_lds(                                          \
        (const __attribute__((address_space(1))) void*)(gp),                   \
        (__attribute__((address_space(3))) void*)(lp), 16, 0, 0)

// Q is pre-scaled by log2(e)/32 in kprep, so exp(S/32) = exp2(S') = one v_exp.
#if __has_builtin(__builtin_amdgcn_exp2f)
#define EXPS(x) __builtin_amdgcn_exp2f(x)
#else
#define EXPS(x) __expf((x) * 0.6931472f)
#endif

#define QSCALE 0.04508422f   // log2(e)/32

// swizzled LDS tile: 64 elems/row, 8 chunks of 8 bf16; chunk' = chunk ^ (row&7)
static __device__ __forceinline__ int swz(int row, int chunk) {
    return (row << 6) + (((chunk) ^ (row & 7)) << 3);
}

static __device__ __forceinline__ bf16x4 cvt4(float4 v) {
    bf16x4 r;
    r[0] = (__bf16)v.x; r[1] = (__bf16)v.y; r[2] = (__bf16)v.z; r[3] = (__bf16)v.w;
    return r;
}

// RTNE f32 pair -> packed 2xbf16 dword, no-NaN fast path (E = exp2(s) is
// always positive/finite). RTNE: u += 0x7FFF + lsb(u>>16); take high half.
// ~6 VALU/pair vs compiler's NaN-quieting sequence.
static __device__ __forceinline__ unsigned pkbf16(float a, float b) {
    unsigned ua = __builtin_bit_cast(unsigned, a);
    unsigned ub = __builtin_bit_cast(unsigned, b);
    ua += 0x7FFFu + ((ua >> 16) & 1u);
    ub += 0x7FFFu + ((ub >> 16) & 1u);
    return (ua >> 16) | (ub & 0xFFFF0000u);
}

// ---------------------------------------------------------------------------
// kprep_all: one launch for Q-prep (pre-scaled), K-prep, W-convert.
// ---------------------------------------------------------------------------
__global__ void kprep_all(const float* __restrict__ q, const float* __restrict__ k,
                          const float* __restrict__ W,
                          __bf16* __restrict__ Qh, __bf16* __restrict__ Kh,
                          __bf16* __restrict__ Wb) {
    int bid = blockIdx.x;
    if (bid < 8192) {
        const float* src = (bid < 4096) ? q : k;
        __bf16* dst = (bid < 4096) ? Qh : Kh;
        const float sc = (bid < 4096) ? QSCALE : 1.0f;
        size_t g = (size_t)(bid & 4095) * 256 + threadIdx.x;
        size_t o = g * 8;
        int c  = (int)(o & 63);
        int s  = (int)((o >> 6) & 2047);
        int bh = (int)(o >> 17);
        int b = bh >> 4, h = bh & 15;
        const float* p = src + ((size_t)(b * SQ + s)) * DM + h * HD + c;
        float4 v0 = *(const float4*)p;
        float4 v1 = *(const float4*)(p + 4);
        bf16x8 r;
        r[0] = (__bf16)(v0.x * sc); r[1] = (__bf16)(v0.y * sc);
        r[2] = (__bf16)(v0.z * sc); r[3] = (__bf16)(v0.w * sc);
        r[4] = (__bf16)(v1.x * sc); r[5] = (__bf16)(v1.y * sc);
        r[6] = (__bf16)(v1.z * sc); r[7] = (__bf16)(v1.w * sc);
        *(bf16x8*)(dst + o) = r;
    } else {
        int i = (bid - 8192) * 256 + threadIdx.x;
        float4 v = *(const float4*)(W + (size_t)i * 4);
        *(bf16x4*)(Wb + (size_t)i * 4) = cvt4(v);
    }
}

// ---------------------------------------------------------------------------
// kz: Z[k] = sum_q exp2(S'); epilogue writes Vt[bh][d][k] = bf16(V/Z)
// 512 threads / 8 waves; qt unrolled by 2 (compile-time buffer selects).
// ---------------------------------------------------------------------------
__global__ __launch_bounds__(512, 4) void kz(const __bf16* __restrict__ Qh,
                                             const __bf16* __restrict__ Kh,
                                             const __bf16* __restrict__ vv,
                                             __bf16* __restrict__ Vt) {
    const float* v = (const float*)vv;   // V input is fp32
    const int bh = blockIdx.x;
    const int kb = blockIdx.y;
    const int b = bh >> 4, h = bh & 15;
    const int t = threadIdx.x;
    const int w = t >> 6, lane = t & 63;
    const int lo16 = lane & 15, quad = lane >> 4;
    const int wub = (t & 448) << 3;          // wave-uniform chunk base (elems)

    __shared__ __bf16 Ks[256 * 64];
    __shared__ __bf16 Qs[2][64 * 64];
    __shared__ float  Zs[256];

    const __bf16* kbase = Kh + ((size_t)bh * SKV + kb * 256) * HD;
    const __bf16* qbase = Qh + (size_t)bh * SQ * HD;

#pragma unroll
    for (int i = 0; i < 4; ++i) {
        int ci = i * 512 + t;
        int row = ci >> 3;
        int c = (ci & 7) ^ (row & 7);
        ASYNC16(kbase + row * 64 + c * 8, &Ks[i * 4096 + wub]);
    }
    {
        int ci = t;
        int row = ci >> 3;
        int c = (ci & 7) ^ (row & 7);
        ASYNC16(qbase + row * 64 + c * 8, &Qs[0][wub]);
    }
    __syncthreads();

    // hoist K fragments (B-operand: n = k-col, kdim = d); wave owns 32 k-cols
    bf16x8 bk[2][2];
#pragma unroll
    for (int nt = 0; nt < 2; ++nt)
#pragma unroll
        for (int dh = 0; dh < 2; ++dh)
            bk[nt][dh] = *(const bf16x8*)(&Ks[swz(w * 32 + nt * 16 + lo16, dh * 4 + quad)]);

    float zacc[2] = {0.f, 0.f};

    // per-lane staging address pieces (loop-invariant)
    const int srow = t >> 3;
    const int scol = ((t & 7) ^ (srow & 7)) * 8;
    const __bf16* qsrc = qbase + srow * 64 + scol;

    auto QTILE = [&](int qt, int cur) {
        const int nxt = cur ^ 1;
        if (qt < 31)
            ASYNC16(qsrc + (size_t)(qt + 1) * 64 * HD, &Qs[nxt][wub]);

        __builtin_amdgcn_s_setprio(1);
#pragma unroll
        for (int mt = 0; mt < 4; ++mt) {
            bf16x8 aq0 = *(const bf16x8*)(&Qs[cur][swz(mt * 16 + lo16, quad)]);
            bf16x8 aq1 = *(const bf16x8*)(&Qs[cur][swz(mt * 16 + lo16, 4 + quad)]);
#pragma unroll
            for (int nt = 0; nt < 2; ++nt) {
                f32x4 acc = {0.f, 0.f, 0.f, 0.f};
                acc = __builtin_amdgcn_mfma_f32_16x16x32_bf16(aq0, bk[nt][0], acc, 0, 0, 0);
                acc = __builtin_amdgcn_mfma_f32_16x16x32_bf16(aq1, bk[nt][1], acc, 0, 0, 0);
                zacc[nt] += (EXPS(acc[0]) + EXPS(acc[1])) + (EXPS(acc[2]) + EXPS(acc[3]));
            }
        }
        __builtin_amdgcn_s_setprio(0);
        __syncthreads();
    };

    for (int qt2 = 0; qt2 < 32; qt2 += 2) {
        QTILE(qt2, 0);
        QTILE(qt2 + 1, 1);
    }

#pragma unroll
    for (int nt = 0; nt < 2; ++nt) {
        float s = zacc[nt];
        s += __shfl_xor(s, 16, 64);
        s += __shfl_xor(s, 32, 64);
        if (lane < 16) Zs[w * 32 + nt * 16 + lane] = s;
    }
    __syncthreads();

    // epilogue: Vt[bh][d][kb*256 + kcol] = bf16(V[k][d] / Z[k])
    {
        int kcol = t & 255, dh2 = t >> 8;
        float rz = 1.0f / Zs[kcol];
        const float* vrow = v + ((size_t)(b * SKV) + kb * 256 + kcol) * DM + h * HD + dh2 * 32;
        size_t vtb = (size_t)bh * HD * SKV + kb * 256 + kcol;
#pragma unroll
        for (int dc = 0; dc < 2; ++dc) {
            float4 a0 = *(const float4*)(vrow + dc * 16 + 0);
            float4 a1 = *(const float4*)(vrow + dc * 16 + 4);
            float4 a2 = *(const float4*)(vrow + dc * 16 + 8);
            float4 a3 = *(const float4*)(vrow + dc * 16 + 12);
            float tmp[16] = {a0.x, a0.y, a0.z, a0.w, a1.x, a1.y, a1.z, a1.w,
                             a2.x, a2.y, a2.z, a2.w, a3.x, a3.y, a3.z, a3.w};
#pragma unroll
            for (int j = 0; j < 16; ++j)
                Vt[vtb + (size_t)(dh2 * 32 + dc * 16 + j) * SKV] = (__bf16)(tmp[j] * rz);
        }
    }
}

// ---------------------------------------------------------------------------
// kattn: O[q,:] = sum_k exp2(S'[q,k]) * Vt[:,k]   (Vt pre-scaled by 1/Z)
// S^T formulation, round-5 verified register-E datapath (permlane swaps),
// kt unrolled by 2 so buffer selects are compile-time immediates.
// LDS = Ks 16K + Vts 16K = 32 KB; grid-capped at 2 blocks/CU.
// ---------------------------------------------------------------------------
__global__ __launch_bounds__(512, 4) void kattn(const __bf16* __restrict__ Qh,
                                                const __bf16* __restrict__ Kh,
                                                const __bf16* __restrict__ Vt,
                                                __bf16* __restrict__ O) {
    const int bh = blockIdx.x;
    const int qb = blockIdx.y;
    const int b = bh >> 4, h = bh & 15;
    const int t = threadIdx.x;
    const int w = t >> 6, lane = t & 63;
    const int lo16 = lane & 15, quad = lane >> 4;
    const int wub = (t & 448) << 3;

    __shared__ __bf16 Ks[2][64 * 64];
    __shared__ __bf16 Vts[2][64 * 64];

    const __bf16* qgb = Qh + ((size_t)bh * SQ + qb * 256 + w * 32) * HD;
    const __bf16* kgbase = Kh + (size_t)bh * SKV * HD;
    const __bf16* vtgbase = Vt + (size_t)bh * HD * SKV;

    // per-lane staging address pieces (loop-invariant)
    const int srow = t >> 3;
    const int scol = ((t & 7) ^ (srow & 7)) * 8;
    const __bf16* ksrc = kgbase + srow * 64 + scol;
    const __bf16* vsrc = vtgbase + (size_t)srow * SKV + scol;

    // stage K/Vt tile 0
    ASYNC16(ksrc, &Ks[0][wub]);
    ASYNC16(vsrc, &Vts[0][wub]);

    // Q fragments (B-operand: n = q, kdim = d), direct from global, persist
    bf16x8 qf[2][2];
#pragma unroll
    for (int qt = 0; qt < 2; ++qt)
#pragma unroll
        for (int dh = 0; dh < 2; ++dh)
            qf[qt][dh] = *(const bf16x8*)(qgb + (size_t)(qt * 16 + lo16) * HD
                                          + (dh * 4 + quad) * 8);

    f32x4 oacc[2][4];
    f32x4 zero = {0.f, 0.f, 0.f, 0.f};
#pragma unroll
    for (int qt = 0; qt < 2; ++qt)
#pragma unroll
        for (int nt = 0; nt < 4; ++nt)
            oacc[qt][nt] = zero;

    __syncthreads();

    auto TILE = [&](int kt, int cur) {
        const int nxt = cur ^ 1;
        if (kt < 31) {
            ASYNC16(ksrc + (size_t)(kt + 1) * 64 * HD, &Ks[nxt][wub]);
            ASYNC16(vsrc + (kt + 1) * 64, &Vts[nxt][wub]);
        }

        __builtin_amdgcn_s_setprio(1);
        // two 32-k groups per 64-k tile; PV consumes each group from registers
#pragma unroll
        for (int g = 0; g < 2; ++g) {
            unsigned pk[2][2][2];   // [T = tile-in-group][qt][pair p]
#pragma unroll
            for (int tt = 0; tt < 2; ++tt) {
                int krow = (g * 2 + tt) * 16 + lo16;
                bf16x8 ak0 = *(const bf16x8*)(&Ks[cur][swz(krow, quad)]);
                bf16x8 ak1 = *(const bf16x8*)(&Ks[cur][swz(krow, 4 + quad)]);
#pragma unroll
                for (int qt = 0; qt < 2; ++qt) {
                    f32x4 s = zero;
                    s = __builtin_amdgcn_mfma_f32_16x16x32_bf16(ak0, qf[qt][0], s, 0, 0, 0);
                    s = __builtin_amdgcn_mfma_f32_16x16x32_bf16(ak1, qf[qt][1], s, 0, 0, 0);
                    pk[tt][qt][0] = pkbf16(EXPS(s[0]), EXPS(s[1]));
                    pk[tt][qt][1] = pkbf16(EXPS(s[2]), EXPS(s[3]));
                }
            }

            // redistribute E to PV A-fragment layout, then PV MFMAs
            bf16x8 ae[2];
#pragma unroll
            for (int qt = 0; qt < 2; ++qt) {
                unsigned j0 = pk[0][qt][0], j2 = pk[1][qt][0];
                unsigned j1 = pk[0][qt][1], j3 = pk[1][qt][1];
                asm("v_permlane32_swap_b32 %0, %1" : "+v"(j0), "+v"(j2));
                asm("v_permlane16_swap_b32 %0, %1" : "+v"(j0), "+v"(j2));
                asm("v_permlane32_swap_b32 %0, %1" : "+v"(j1), "+v"(j3));
                asm("v_permlane16_swap_b32 %0, %1" : "+v"(j1), "+v"(j3));
                uint4 u;
                u.x = j0; u.y = j1; u.z = j2; u.w = j3;
                ae[qt] = __builtin_bit_cast(bf16x8, u);
            }

#pragma unroll
            for (int nt = 0; nt < 4; ++nt) {
                bf16x8 bv = *(const bf16x8*)(&Vts[cur][swz(nt * 16 + lo16, g * 4 + quad)]);
#pragma unroll
                for (int qt = 0; qt < 2; ++qt)
                    oacc[qt][nt] = __builtin_amdgcn_mfma_f32_16x16x32_bf16(ae[qt], bv, oacc[qt][nt], 0, 0, 0);
            }
        }
        __builtin_amdgcn_s_setprio(0);
        __syncthreads();
    };

    for (int kt2 = 0; kt2 < 32; kt2 += 2) {
        TILE(kt2, 0);
        TILE(kt2 + 1, 1);
    }

    size_t obase = ((size_t)(b * SQ) + qb * 256 + w * 32) * DM + h * HD;
#pragma unroll
    for (int qt = 0; qt < 2; ++qt)
#pragma unroll
        for (int nt = 0; nt < 4; ++nt)
#pragma unroll
            for (int r = 0; r < 4; ++r)
                O[obase + (size_t)(qt * 16 + quad * 4 + r) * DM + nt * 16 + lo16] =
                    (__bf16)oacc[qt][nt][r];
}

// ---------------------------------------------------------------------------
// kproj: out[n, i] = sum_j A[n,j] * W[i,j] + b[i]   (NT GEMM, 128x128 tiles,
// double-buffered). Round-1 verified 256-thread version.
// ---------------------------------------------------------------------------
__global__ __launch_bounds__(256, 2) void kproj(const __bf16* __restrict__ A,
                                                const __bf16* __restrict__ Wb,
                                                const float* __restrict__ bias,
                                                float* __restrict__ out) {
    const int nb = blockIdx.x;
    const int mb = blockIdx.y;
    const int t = threadIdx.x;
    const int w = t >> 6, lane = t & 63;
    const int lo16 = lane & 15, quad = lane >> 4;
    const int wm = w & 1, wn = w >> 1;
    const int wub = (t & 192) << 3;

    __shared__ __bf16 As[2][128 * 64];
    __shared__ __bf16 Bs[2][128 * 64];

    f32x4 acc[4][4];
    f32x4 zero = {0.f, 0.f, 0.f, 0.f};
#pragma unroll
    for (int mt = 0; mt < 4; ++mt)
#pragma unroll
        for (int nt = 0; nt < 4; ++nt)
            acc[mt][nt] = zero;

    const __bf16* abase = A + (size_t)(mb * 128) * DM;
    const __bf16* wbase = Wb + (size_t)(nb * 128) * DM;

#pragma unroll
    for (int i = 0; i < 4; ++i) {
        int ci = i * 256 + t;
        int row = ci >> 3;
        int c = (ci & 7) ^ (row & 7);
        ASYNC16(abase + (size_t)row * DM + c * 8, &As[0][i * 2048 + wub]);
        ASYNC16(wbase + (size_t)row * DM + c * 8, &Bs[0][i * 2048 + wub]);
    }
    __syncthreads();

    for (int kt = 0; kt < 16; ++kt) {
        const int cur = kt & 1, nxt = cur ^ 1;
        if (kt < 15) {
#pragma unroll
            for (int i = 0; i < 4; ++i) {
                int ci = i * 256 + t;
                int row = ci >> 3;
                int c = (ci & 7) ^ (row & 7);
                ASYNC16(abase + (size_t)row * DM + (kt + 1) * 64 + c * 8, &As[nxt][i * 2048 + wub]);
                ASYNC16(wbase + (size_t)row * DM + (kt + 1) * 64 + c * 8, &Bs[nxt][i * 2048 + wub]);
            }
        }

#pragma unroll
        for (int ks = 0; ks < 2; ++ks) {
            bf16x8 av[4], bv[4];
#pragma unroll
            for (int mt = 0; mt < 4; ++mt)
                av[mt] = *(const bf16x8*)(&As[cur][swz(wm * 64 + mt * 16 + lo16, ks * 4 + quad)]);
#pragma unroll
            for (int nt = 0; nt < 4; ++nt)
                bv[nt] = *(const bf16x8*)(&Bs[cur][swz(wn * 64 + nt * 16 + lo16, ks * 4 + quad)]);
#pragma unroll
            for (int mt = 0; mt < 4; ++mt)
#pragma unroll
                for (int nt = 0; nt < 4; ++nt)
                    acc[mt][nt] = __builtin_amdgcn_mfma_f32_16x16x32_bf16(av[mt], bv[nt], acc[mt][nt], 0, 0, 0);
        }
        __syncthreads();
    }

    const int col0 = nb * 128 + wn * 64;
    const int row0 = mb * 128 + wm * 64;
#pragma unroll
    for (int nt = 0; nt < 4; ++nt) {
        float bb = bias[col0 + nt * 16 + lo16];
#pragma unroll
        for (int mt = 0; mt < 4; ++mt)
#pragma unroll
            for (int r = 0; r < 4; ++r)
                out[(size_t)(row0 + mt * 16 + quad * 4 + r) * DM + col0 + nt * 16 + lo16] =
                    acc[mt][nt][r] + bb;
    }
}

// ---------------------------------------------------------------------------
extern "C" void kernel_launch(void* const* d_in, const int* in_sizes, int n_in,
                              void* d_out, int out_size, void* d_ws, size_t ws_size,
                              hipStream_t stream) {
    const float* q    = (const float*)d_in[0];
    const float* k    = (const float*)d_in[1];
    const float* v    = (const float*)d_in[2];
    const float* W    = (const float*)d_in[3];
    const float* bias = (const float*)d_in[4];
    float* out = (float*)d_out;

    char* ws = (char*)d_ws;
    __bf16* Qh = (__bf16*)ws;                          // 16 MB
    __bf16* Kh = (__bf16*)(ws + (16u << 20));          // 16 MB
    __bf16* Vt = (__bf16*)(ws + (32u << 20));          // 16 MB
    __bf16* Wb = (__bf16*)(ws + (48u << 20));          // 2 MB
    __bf16* O  = (__bf16*)(ws + (50u << 20));          // 16 MB

    kprep_all<<<dim3(9216), 256, 0, stream>>>(q, k, W, Qh, Kh, Wb);
    kz       <<<dim3(64, 8), 512, 0, stream>>>(Qh, Kh, (const __bf16*)v, Vt);
    kattn    <<<dim3(64, 8), 512, 0, stream>>>(Qh, Kh, Vt, O);
    kproj    <<<dim3(8, 64), 256, 0, stream>>>(O, Wb, bias, out);
}

// Round 9
// 289.687 us; speedup vs baseline: 1.0235x; 1.0235x over previous
//
#include <hip/hip_runtime.h>

#define NH    16
#define HD    64
#define SQ    2048
#define SKV   2048
#define DM    1024

typedef __attribute__((ext_vector_type(8))) __bf16 bf16x8;
typedef __attribute__((ext_vector_type(4))) __bf16 bf16x4;
typedef __attribute__((ext_vector_type(2))) __bf16 bf16x2;
typedef __attribute__((ext_vector_type(4))) float  f32x4;

// async global->LDS, 16B per lane; LDS dest = wave-uniform base + lane*16
#define ASYNC16(gp, lp)                                                        \
    __builtin_amdgcn_global_load_lds(                                          \
        (const __attribute__((address_space(1))) void*)(gp),                   \
        (__attribute__((address_space(3))) void*)(lp), 16, 0, 0)

// Q is pre-scaled by log2(e)/32 in kprep, so exp(S/32) = exp2(S') = one v_exp.
#if __has_builtin(__builtin_amdgcn_exp2f)
#define EXPS(x) __builtin_amdgcn_exp2f(x)
#else
#define EXPS(x) __expf((x) * 0.6931472f)
#endif

#define QSCALE 0.04508422f   // log2(e)/32

// swizzled LDS tile: 64 elems/row, 8 chunks of 8 bf16; chunk' = chunk ^ (row&7)
static __device__ __forceinline__ int swz(int row, int chunk) {
    return (row << 6) + (((chunk) ^ (row & 7)) << 3);
}

static __device__ __forceinline__ bf16x4 cvt4(float4 v) {
    bf16x4 r;
    r[0] = (__bf16)v.x; r[1] = (__bf16)v.y; r[2] = (__bf16)v.z; r[3] = (__bf16)v.w;
    return r;
}

// truncate positive f32 to the bf16 grid (RTZ) — bit-identical to what
// v_cvt_pk_bf16_f32 produces for the PV operand (empirical: r2 vs r5).
static __device__ __forceinline__ float truncbf(float a) {
    unsigned u = __builtin_bit_cast(unsigned, a) & 0xFFFF0000u;
    return __builtin_bit_cast(float, u);
}

// ---------------------------------------------------------------------------
// kprep_all: one launch for Q-prep (pre-scaled by log2e/32), K-prep, W-convert.
// ---------------------------------------------------------------------------
__global__ void kprep_all(const float* __restrict__ q, const float* __restrict__ k,
                          const float* __restrict__ W,
                          __bf16* __restrict__ Qh, __bf16* __restrict__ Kh,
                          __bf16* __restrict__ Wb) {
    int bid = blockIdx.x;
    if (bid < 8192) {
        const float* src = (bid < 4096) ? q : k;
        __bf16* dst = (bid < 4096) ? Qh : Kh;
        const float sc = (bid < 4096) ? QSCALE : 1.0f;
        size_t g = (size_t)(bid & 4095) * 256 + threadIdx.x;
        size_t o = g * 8;
        int c  = (int)(o & 63);
        int s  = (int)((o >> 6) & 2047);
        int bh = (int)(o >> 17);
        int b = bh >> 4, h = bh & 15;
        const float* p = src + ((size_t)(b * SQ + s)) * DM + h * HD + c;
        float4 v0 = *(const float4*)p;
        float4 v1 = *(const float4*)(p + 4);
        bf16x8 r;
        r[0] = (__bf16)(v0.x * sc); r[1] = (__bf16)(v0.y * sc);
        r[2] = (__bf16)(v0.z * sc); r[3] = (__bf16)(v0.w * sc);
        r[4] = (__bf16)(v1.x * sc); r[5] = (__bf16)(v1.y * sc);
        r[6] = (__bf16)(v1.z * sc); r[7] = (__bf16)(v1.w * sc);
        *(bf16x8*)(dst + o) = r;
    } else {
        int i = (bid - 8192) * 256 + threadIdx.x;
        float4 v = *(const float4*)(W + (size_t)i * 4);
        *(bf16x4*)(Wb + (size_t)i * 4) = cvt4(v);
    }
}

// ---------------------------------------------------------------------------
// kz: Z[k] = sum_q truncbf(exp2(S')); epilogue writes Vt[bh][d][k] = bf16(V/Z)
// Z sums the SAME bf16-truncated values kattn's cvt_pk feeds to PV, so the
// truncation bias cancels in O = sum(E'V)/Z. 512 threads / 8 waves (r5 base).
// ---------------------------------------------------------------------------
__global__ __launch_bounds__(512, 4) void kz(const __bf16* __restrict__ Qh,
                                             const __bf16* __restrict__ Kh,
                                             const __bf16* __restrict__ vv,
                                             __bf16* __restrict__ Vt) {
    const float* v = (const float*)vv;   // V input is fp32
    const int bh = blockIdx.x;
    const int kb = blockIdx.y;
    const int b = bh >> 4, h = bh & 15;
    const int t = threadIdx.x;
    const int w = t >> 6, lane = t & 63;
    const int lo16 = lane & 15, quad = lane >> 4;
    const int wub = (t & 448) << 3;          // wave-uniform chunk base (elems)

    __shared__ __bf16 Ks[256 * 64];
    __shared__ __bf16 Qs[2][64 * 64];
    __shared__ float  Zs[256];

    const __bf16* kbase = Kh + ((size_t)bh * SKV + kb * 256) * HD;
    const __bf16* qbase = Qh + (size_t)bh * SQ * HD;

#pragma unroll
    for (int i = 0; i < 4; ++i) {
        int ci = i * 512 + t;
        int row = ci >> 3;
        int c = (ci & 7) ^ (row & 7);
        ASYNC16(kbase + row * 64 + c * 8, &Ks[i * 4096 + wub]);
    }
    {
        int ci = t;
        int row = ci >> 3;
        int c = (ci & 7) ^ (row & 7);
        ASYNC16(qbase + row * 64 + c * 8, &Qs[0][wub]);
    }
    __syncthreads();

    // hoist K fragments (B-operand: n = k-col, kdim = d); wave owns 32 k-cols
    bf16x8 bk[2][2];
#pragma unroll
    for (int nt = 0; nt < 2; ++nt)
#pragma unroll
        for (int dh = 0; dh < 2; ++dh)
            bk[nt][dh] = *(const bf16x8*)(&Ks[swz(w * 32 + nt * 16 + lo16, dh * 4 + quad)]);

    float zacc[2] = {0.f, 0.f};

    for (int qt = 0; qt < 32; ++qt) {
        const int cur = qt & 1, nxt = cur ^ 1;
        if (qt < 31) {
            int ci = t;
            int row = ci >> 3;
            int c = (ci & 7) ^ (row & 7);
            ASYNC16(qbase + (size_t)(qt + 1) * 64 * HD + row * 64 + c * 8,
                    &Qs[nxt][wub]);
        }

        __builtin_amdgcn_s_setprio(1);
#pragma unroll
        for (int mt = 0; mt < 4; ++mt) {
            bf16x8 aq0 = *(const bf16x8*)(&Qs[cur][swz(mt * 16 + lo16, quad)]);
            bf16x8 aq1 = *(const bf16x8*)(&Qs[cur][swz(mt * 16 + lo16, 4 + quad)]);
#pragma unroll
            for (int nt = 0; nt < 2; ++nt) {
                f32x4 acc = {0.f, 0.f, 0.f, 0.f};
                acc = __builtin_amdgcn_mfma_f32_16x16x32_bf16(aq0, bk[nt][0], acc, 0, 0, 0);
                acc = __builtin_amdgcn_mfma_f32_16x16x32_bf16(aq1, bk[nt][1], acc, 0, 0, 0);
                zacc[nt] += (truncbf(EXPS(acc[0])) + truncbf(EXPS(acc[1])))
                          + (truncbf(EXPS(acc[2])) + truncbf(EXPS(acc[3])));
            }
        }
        __builtin_amdgcn_s_setprio(0);
        __syncthreads();
    }

#pragma unroll
    for (int nt = 0; nt < 2; ++nt) {
        float s = zacc[nt];
        s += __shfl_xor(s, 16, 64);
        s += __shfl_xor(s, 32, 64);
        if (lane < 16) Zs[w * 32 + nt * 16 + lane] = s;
    }
    __syncthreads();

    // epilogue: Vt[bh][d][kb*256 + kcol] = bf16(V[k][d] / Z[k])
    {
        int kcol = t & 255, dh2 = t >> 8;
        float rz = 1.0f / Zs[kcol];
        const float* vrow = v + ((size_t)(b * SKV) + kb * 256 + kcol) * DM + h * HD + dh2 * 32;
        size_t vtb = (size_t)bh * HD * SKV + kb * 256 + kcol;
#pragma unroll
        for (int dc = 0; dc < 2; ++dc) {
            float4 a0 = *(const float4*)(vrow + dc * 16 + 0);
            float4 a1 = *(const float4*)(vrow + dc * 16 + 4);
            float4 a2 = *(const float4*)(vrow + dc * 16 + 8);
            float4 a3 = *(const float4*)(vrow + dc * 16 + 12);
            float tmp[16] = {a0.x, a0.y, a0.z, a0.w, a1.x, a1.y, a1.z, a1.w,
                             a2.x, a2.y, a2.z, a2.w, a3.x, a3.y, a3.z, a3.w};
#pragma unroll
            for (int j = 0; j < 16; ++j)
                Vt[vtb + (size_t)(dh2 * 32 + dc * 16 + j) * SKV] = (__bf16)(tmp[j] * rz);
        }
    }
}

// ---------------------------------------------------------------------------
// kattn: O[q,:] = sum_k exp2(S'[q,k]) * Vt[:,k]   (Vt pre-scaled by 1/Z)
// S^T formulation, r5-verified register-E datapath (permlane swaps); the
// f32->2xbf16 pack is a single v_cvt_pk_bf16_f32 per pair (truncating — the
// bias is cancelled by kz's truncated Z). LDS = 32 KB; 2 blocks/CU.
// ---------------------------------------------------------------------------
__global__ __launch_bounds__(512, 4) void kattn(const __bf16* __restrict__ Qh,
                                                const __bf16* __restrict__ Kh,
                                                const __bf16* __restrict__ Vt,
                                                __bf16* __restrict__ O) {
    const int bh = blockIdx.x;
    const int qb = blockIdx.y;
    const int b = bh >> 4, h = bh & 15;
    const int t = threadIdx.x;
    const int w = t >> 6, lane = t & 63;
    const int lo16 = lane & 15, quad = lane >> 4;
    const int wub = (t & 448) << 3;

    __shared__ __bf16 Ks[2][64 * 64];
    __shared__ __bf16 Vts[2][64 * 64];

    const __bf16* qgb = Qh + ((size_t)bh * SQ + qb * 256 + w * 32) * HD;
    const __bf16* kgbase = Kh + (size_t)bh * SKV * HD;
    const __bf16* vtgbase = Vt + (size_t)bh * HD * SKV;

    // stage K/Vt tile 0 (one ASYNC16 per thread per buffer)
    {
        int ci = t;
        int row = ci >> 3;
        int c = (ci & 7) ^ (row & 7);
        ASYNC16(kgbase + row * 64 + c * 8, &Ks[0][wub]);
        ASYNC16(vtgbase + (size_t)row * SKV + c * 8, &Vts[0][wub]);
    }

    // Q fragments (B-operand: n = q, kdim = d), direct from global, persist
    bf16x8 qf[2][2];
#pragma unroll
    for (int qt = 0; qt < 2; ++qt)
#pragma unroll
        for (int dh = 0; dh < 2; ++dh)
            qf[qt][dh] = *(const bf16x8*)(qgb + (size_t)(qt * 16 + lo16) * HD
                                          + (dh * 4 + quad) * 8);

    f32x4 oacc[2][4];
    f32x4 zero = {0.f, 0.f, 0.f, 0.f};
#pragma unroll
    for (int qt = 0; qt < 2; ++qt)
#pragma unroll
        for (int nt = 0; nt < 4; ++nt)
            oacc[qt][nt] = zero;

    __syncthreads();

    for (int kt = 0; kt < 32; ++kt) {
        const int cur = kt & 1, nxt = cur ^ 1;
        if (kt < 31) {
            int ci = t;
            int row = ci >> 3;
            int c = (ci & 7) ^ (row & 7);
            ASYNC16(kgbase + (size_t)(kt + 1) * 64 * HD + row * 64 + c * 8,
                    &Ks[nxt][wub]);
            ASYNC16(vtgbase + (size_t)row * SKV + (kt + 1) * 64 + c * 8,
                    &Vts[nxt][wub]);
        }

        __builtin_amdgcn_s_setprio(1);
        // two 32-k groups per 64-k tile; PV consumes each group from registers
#pragma unroll
        for (int g = 0; g < 2; ++g) {
            unsigned pk[2][2][2];   // [T = tile-in-group][qt][pair p]
#pragma unroll
            for (int tt = 0; tt < 2; ++tt) {
                int krow = (g * 2 + tt) * 16 + lo16;
                bf16x8 ak0 = *(const bf16x8*)(&Ks[cur][swz(krow, quad)]);
                bf16x8 ak1 = *(const bf16x8*)(&Ks[cur][swz(krow, 4 + quad)]);
#pragma unroll
                for (int qt = 0; qt < 2; ++qt) {
                    f32x4 s = zero;
                    s = __builtin_amdgcn_mfma_f32_16x16x32_bf16(ak0, qf[qt][0], s, 0, 0, 0);
                    s = __builtin_amdgcn_mfma_f32_16x16x32_bf16(ak1, qf[qt][1], s, 0, 0, 0);
                    float e0 = EXPS(s[0]), e1 = EXPS(s[1]);
                    float e2 = EXPS(s[2]), e3 = EXPS(s[3]);
                    unsigned dlo, dhi;
                    asm("v_cvt_pk_bf16_f32 %0, %1, %2"
                        : "=v"(dlo) : "v"(e0), "v"(e1));
                    asm("v_cvt_pk_bf16_f32 %0, %1, %2"
                        : "=v"(dhi) : "v"(e2), "v"(e3));
                    pk[tt][qt][0] = dlo;
                    pk[tt][qt][1] = dhi;
                }
            }

            // redistribute E to PV A-fragment layout, then PV MFMAs
            bf16x8 ae[2];
#pragma unroll
            for (int qt = 0; qt < 2; ++qt) {
                unsigned j0 = pk[0][qt][0], j2 = pk[1][qt][0];
                unsigned j1 = pk[0][qt][1], j3 = pk[1][qt][1];
                asm("v_permlane32_swap_b32 %0, %1" : "+v"(j0), "+v"(j2));
                asm("v_permlane16_swap_b32 %0, %1" : "+v"(j0), "+v"(j2));
                asm("v_permlane32_swap_b32 %0, %1" : "+v"(j1), "+v"(j3));
                asm("v_permlane16_swap_b32 %0, %1" : "+v"(j1), "+v"(j3));
                uint4 u;
                u.x = j0; u.y = j1; u.z = j2; u.w = j3;
                ae[qt] = __builtin_bit_cast(bf16x8, u);
            }

#pragma unroll
            for (int nt = 0; nt < 4; ++nt) {
                bf16x8 bv = *(const bf16x8*)(&Vts[cur][swz(nt * 16 + lo16, g * 4 + quad)]);
#pragma unroll
                for (int qt = 0; qt < 2; ++qt)
                    oacc[qt][nt] = __builtin_amdgcn_mfma_f32_16x16x32_bf16(ae[qt], bv, oacc[qt][nt], 0, 0, 0);
            }
        }
        __builtin_amdgcn_s_setprio(0);
        __syncthreads();
    }

    size_t obase = ((size_t)(b * SQ) + qb * 256 + w * 32) * DM + h * HD;
#pragma unroll
    for (int qt = 0; qt < 2; ++qt)
#pragma unroll
        for (int nt = 0; nt < 4; ++nt)
#pragma unroll
            for (int r = 0; r < 4; ++r)
                O[obase + (size_t)(qt * 16 + quad * 4 + r) * DM + nt * 16 + lo16] =
                    (__bf16)oacc[qt][nt][r];
}

// ---------------------------------------------------------------------------
// kproj: out[n, i] = sum_j A[n,j] * W[i,j] + b[i]   (NT GEMM, 128x128 tiles,
// double-buffered). Round-1 verified 256-thread version.
// ---------------------------------------------------------------------------
__global__ __launch_bounds__(256, 2) void kproj(const __bf16* __restrict__ A,
                                                const __bf16* __restrict__ Wb,
                                                const float* __restrict__ bias,
                                                float* __restrict__ out) {
    const int nb = blockIdx.x;
    const int mb = blockIdx.y;
    const int t = threadIdx.x;
    const int w = t >> 6, lane = t & 63;
    const int lo16 = lane & 15, quad = lane >> 4;
    const int wm = w & 1, wn = w >> 1;
    const int wub = (t & 192) << 3;

    __shared__ __bf16 As[2][128 * 64];
    __shared__ __bf16 Bs[2][128 * 64];

    f32x4 acc[4][4];
    f32x4 zero = {0.f, 0.f, 0.f, 0.f};
#pragma unroll
    for (int mt = 0; mt < 4; ++mt)
#pragma unroll
        for (int nt = 0; nt < 4; ++nt)
            acc[mt][nt] = zero;

    const __bf16* abase = A + (size_t)(mb * 128) * DM;
    const __bf16* wbase = Wb + (size_t)(nb * 128) * DM;

#pragma unroll
    for (int i = 0; i < 4; ++i) {
        int ci = i * 256 + t;
        int row = ci >> 3;
        int c = (ci & 7) ^ (row & 7);
        ASYNC16(abase + (size_t)row * DM + c * 8, &As[0][i * 2048 + wub]);
        ASYNC16(wbase + (size_t)row * DM + c * 8, &Bs[0][i * 2048 + wub]);
    }
    __syncthreads();

    for (int kt = 0; kt < 16; ++kt) {
        const int cur = kt & 1, nxt = cur ^ 1;
        if (kt < 15) {
#pragma unroll
            for (int i = 0; i < 4; ++i) {
                int ci = i * 256 + t;
                int row = ci >> 3;
                int c = (ci & 7) ^ (row & 7);
                ASYNC16(abase + (size_t)row * DM + (kt + 1) * 64 + c * 8, &As[nxt][i * 2048 + wub]);
                ASYNC16(wbase + (size_t)row * DM + (kt + 1) * 64 + c * 8, &Bs[nxt][i * 2048 + wub]);
            }
        }

#pragma unroll
        for (int ks = 0; ks < 2; ++ks) {
            bf16x8 av[4], bv[4];
#pragma unroll
            for (int mt = 0; mt < 4; ++mt)
                av[mt] = *(const bf16x8*)(&As[cur][swz(wm * 64 + mt * 16 + lo16, ks * 4 + quad)]);
#pragma unroll
            for (int nt = 0; nt < 4; ++nt)
                bv[nt] = *(const bf16x8*)(&Bs[cur][swz(wn * 64 + nt * 16 + lo16, ks * 4 + quad)]);
#pragma unroll
            for (int mt = 0; mt < 4; ++mt)
#pragma unroll
                for (int nt = 0; nt < 4; ++nt)
                    acc[mt][nt] = __builtin_amdgcn_mfma_f32_16x16x32_bf16(av[mt], bv[nt], acc[mt][nt], 0, 0, 0);
        }
        __syncthreads();
    }

    const int col0 = nb * 128 + wn * 64;
    const int row0 = mb * 128 + wm * 64;
#pragma unroll
    for (int nt = 0; nt < 4; ++nt) {
        float bb = bias[col0 + nt * 16 + lo16];
#pragma unroll
        for (int mt = 0; mt < 4; ++mt)
#pragma unroll
            for (int r = 0; r < 4; ++r)
                out[(size_t)(row0 + mt * 16 + quad * 4 + r) * DM + col0 + nt * 16 + lo16] =
                    acc[mt][nt][r] + bb;
    }
}

// ---------------------------------------------------------------------------
extern "C" void kernel_launch(void* const* d_in, const int* in_sizes, int n_in,
                              void* d_out, int out_size, void* d_ws, size_t ws_size,
                              hipStream_t stream) {
    const float* q    = (const float*)d_in[0];
    const float* k    = (const float*)d_in[1];
    const float* v    = (const float*)d_in[2];
    const float* W    = (const float*)d_in[3];
    const float* bias = (const float*)d_in[4];
    float* out = (float*)d_out;

    char* ws = (char*)d_ws;
    __bf16* Qh = (__bf16*)ws;                          // 16 MB
    __bf16* Kh = (__bf16*)(ws + (16u << 20));          // 16 MB
    __bf16* Vt = (__bf16*)(ws + (32u << 20));          // 16 MB
    __bf16* Wb = (__bf16*)(ws + (48u << 20));          // 2 MB
    __bf16* O  = (__bf16*)(ws + (50u << 20));          // 16 MB

    kprep_all<<<dim3(9216), 256, 0, stream>>>(q, k, W, Qh, Kh, Wb);
    kz       <<<dim3(64, 8), 512, 0, stream>>>(Qh, Kh, (const __bf16*)v, Vt);
    kattn    <<<dim3(64, 8), 512, 0, stream>>>(Qh, Kh, Vt, O);
    kproj    <<<dim3(8, 64), 256, 0, stream>>>(O, Wb, bias, out);
}